// Round 1
// baseline (293.015 us; speedup 1.0000x reference)
//
#include <hip/hip_runtime.h>
#include <math.h>

#define G 16  // tokens per round; LDS = 16*4KB x + ~2.6KB small = ~68KB -> 2 blocks/CU

__device__ __forceinline__ float sigmoidf_(float s) {
    return 1.0f / (1.0f + __expf(-s));
}

__global__ __launch_bounds__(256, 2)
void fused_route_mix(const float* __restrict__ x,
                     const float* __restrict__ scale,
                     const float* __restrict__ w_pre,
                     const float* __restrict__ w_post,
                     const float* __restrict__ w_res,
                     const float* __restrict__ ap_p,
                     const float* __restrict__ apo_p,
                     const float* __restrict__ ar_p,
                     const float* __restrict__ b_pre,
                     const float* __restrict__ b_post,
                     const float* __restrict__ b_res,
                     float* __restrict__ out,
                     int rounds)
{
    __shared__ __align__(16) float xs[G * 1024];   // raw x for G tokens
    __shared__ float hraw[G * 24];                 // 24 raw dots per token
    __shared__ float sslds[G];                     // sum of squares per token
    __shared__ __align__(16) float Mlds[G * 16];   // 4x4 mixing matrix per token

    const int t = threadIdx.x;
    const int w = t >> 6;   // wave 0..3
    const int l = t & 63;   // lane 0..63

    // ---- once per block: weight fragments in registers (scale folded in) ----
    // global row k: 0-3 = w_pre, 4-7 = w_post, 8-23 = w_res. wave w owns rows 6w..6w+5.
    // lane l owns elements {l + 64m : m=0..15} of each of its rows.
    float wreg[6][16];
    {
        float scl[16];
        #pragma unroll
        for (int m = 0; m < 16; ++m) scl[m] = scale[l + 64 * m];
        #pragma unroll
        for (int rr = 0; rr < 6; ++rr) {
            const int k = 6 * w + rr;
            const float* wp = (k < 4) ? (w_pre + (size_t)k * 1024)
                            : (k < 8) ? (w_post + (size_t)(k - 4) * 1024)
                                      : (w_res + (size_t)(k - 8) * 1024);
            #pragma unroll
            for (int m = 0; m < 16; ++m)
                wreg[rr][m] = wp[l + 64 * m] * scl[m];
        }
    }

    const float a_pre = ap_p[0], a_post = apo_p[0], a_res = ar_p[0];

    for (int r = blockIdx.x; r < rounds; r += gridDim.x) {
        const size_t base = (size_t)r * (G * 1024);

        // ---- phase 1: stage x (coalesced float4) ----
        const float4* __restrict__ xg = (const float4*)(x + base);
        float4* xs4 = (float4*)xs;
        #pragma unroll
        for (int i = 0; i < G; ++i)
            xs4[i * 256 + t] = xg[i * 256 + t];
        __syncthreads();

        // ---- phase 2: 24 raw dot products per token (+ sum-of-squares on wave 0) ----
        for (int i = 0; i < G; ++i) {
            float p0 = 0.f, p1 = 0.f, p2 = 0.f, p3 = 0.f, p4 = 0.f, p5 = 0.f;
            float ssp = 0.f;
            const float* xi = xs + i * 1024 + l;
            #pragma unroll
            for (int m = 0; m < 16; ++m) {
                const float xv = xi[64 * m];   // bank = l%32, 2-way (free)
                p0 = fmaf(xv, wreg[0][m], p0);
                p1 = fmaf(xv, wreg[1][m], p1);
                p2 = fmaf(xv, wreg[2][m], p2);
                p3 = fmaf(xv, wreg[3][m], p3);
                p4 = fmaf(xv, wreg[4][m], p4);
                p5 = fmaf(xv, wreg[5][m], p5);
                if (w == 0) ssp = fmaf(xv, xv, ssp);
            }
            #pragma unroll
            for (int mask = 1; mask < 64; mask <<= 1) {
                p0 += __shfl_xor(p0, mask);
                p1 += __shfl_xor(p1, mask);
                p2 += __shfl_xor(p2, mask);
                p3 += __shfl_xor(p3, mask);
                p4 += __shfl_xor(p4, mask);
                p5 += __shfl_xor(p5, mask);
                if (w == 0) ssp += __shfl_xor(ssp, mask);
            }
            if (l == 0) {
                float* h = hraw + i * 24 + 6 * w;
                h[0] = p0; h[1] = p1; h[2] = p2;
                h[3] = p3; h[4] = p4; h[5] = p5;
                if (w == 0) sslds[i] = ssp;
            }
        }
        __syncthreads();

        // ---- phase 3: per-token nonlinearity + sinkhorn (token-per-lane, wave 0) ----
        if (t < G) {
            const int tk = t;
            const float inv = rsqrtf(sslds[tk] * (1.0f / 1024.0f) + 1e-5f);
            float hr[24];
            #pragma unroll
            for (int k = 0; k < 24; ++k) hr[k] = hraw[tk * 24 + k];

            float hpre[4], hpost[4];
            #pragma unroll
            for (int j = 0; j < 4; ++j)
                hpre[j] = sigmoidf_(fmaf(a_pre * inv, hr[j], b_pre[j]));
            #pragma unroll
            for (int i = 0; i < 4; ++i)
                hpost[i] = 2.0f * sigmoidf_(fmaf(a_post * inv, hr[4 + i], b_post[i]));

            float K[4][4];
            float mx = -1e30f;
            #pragma unroll
            for (int i = 0; i < 4; ++i) {
                #pragma unroll
                for (int j = 0; j < 4; ++j) {
                    const float vv = fmaf(a_res * inv, hr[8 + 4 * i + j], b_res[4 * i + j]);
                    K[i][j] = vv;
                    mx = fmaxf(mx, vv);
                }
            }
            #pragma unroll
            for (int i = 0; i < 4; ++i)
                #pragma unroll
                for (int j = 0; j < 4; ++j)
                    K[i][j] = __expf(K[i][j] - mx);

            // sinkhorn as scaling vectors: matrix is u_i * K_ij * v_j throughout.
            // col step: dividing col j by (colsum+eps) is exactly v_j /= (v_j*S_j + eps).
            float u[4] = {1.f, 1.f, 1.f, 1.f};
            float v[4] = {1.f, 1.f, 1.f, 1.f};
            for (int it = 0; it < 20; ++it) {
                #pragma unroll
                for (int j = 0; j < 4; ++j) {
                    const float S = u[0] * K[0][j] + u[1] * K[1][j]
                                  + u[2] * K[2][j] + u[3] * K[3][j];
                    v[j] = v[j] * __builtin_amdgcn_rcpf(fmaf(v[j], S, 1e-8f));
                }
                #pragma unroll
                for (int i = 0; i < 4; ++i) {
                    const float T = K[i][0] * v[0] + K[i][1] * v[1]
                                  + K[i][2] * v[2] + K[i][3] * v[3];
                    u[i] = u[i] * __builtin_amdgcn_rcpf(fmaf(u[i], T, 1e-8f));
                }
            }
            #pragma unroll
            for (int i = 0; i < 4; ++i)
                #pragma unroll
                for (int j = 0; j < 4; ++j)
                    Mlds[tk * 16 + 4 * i + j] =
                        fmaf(u[i] * K[i][j], v[j], hpost[i] * hpre[j]);
        }
        __syncthreads();

        // ---- phase 4: mixing, out[i][c] = sum_j M[i][j] * x[j][c] ----
        for (int i = 0; i < G; ++i) {
            const float4 m4 = ((const float4*)Mlds)[i * 4 + w];  // row w, broadcast
            const float4* xt = xs4 + i * 256;
            const float4 a0 = xt[0 * 64 + l];
            const float4 a1 = xt[1 * 64 + l];
            const float4 a2 = xt[2 * 64 + l];
            const float4 a3 = xt[3 * 64 + l];
            float4 o;
            o.x = m4.x * a0.x + m4.y * a1.x + m4.z * a2.x + m4.w * a3.x;
            o.y = m4.x * a0.y + m4.y * a1.y + m4.z * a2.y + m4.w * a3.y;
            o.z = m4.x * a0.z + m4.y * a1.z + m4.z * a2.z + m4.w * a3.z;
            o.w = m4.x * a0.w + m4.y * a1.w + m4.z * a2.w + m4.w * a3.w;
            ((float4*)(out + base))[i * 256 + w * 64 + l] = o;
        }
        __syncthreads();  // protect xs before next round's staging
    }
}

extern "C" void kernel_launch(void* const* d_in, const int* in_sizes, int n_in,
                              void* d_out, int out_size, void* d_ws, size_t ws_size,
                              hipStream_t stream) {
    const float* x      = (const float*)d_in[0];
    const float* scale  = (const float*)d_in[1];
    const float* w_pre  = (const float*)d_in[2];
    const float* w_post = (const float*)d_in[3];
    const float* w_res  = (const float*)d_in[4];
    const float* a_pre  = (const float*)d_in[5];
    const float* a_post = (const float*)d_in[6];
    const float* a_res  = (const float*)d_in[7];
    const float* b_pre  = (const float*)d_in[8];
    const float* b_post = (const float*)d_in[9];
    const float* b_res  = (const float*)d_in[10];
    float* out = (float*)d_out;

    const int tokens = in_sizes[0] / 1024;   // B*T (n*C = 1024)
    const int rounds = tokens / G;
    const int grid = rounds < 1024 ? rounds : 1024;

    fused_route_mix<<<grid, 256, 0, stream>>>(
        x, scale, w_pre, w_post, w_res,
        a_pre, a_post, a_res, b_pre, b_post, b_res,
        out, rounds);
}